// Round 11
// baseline (70.638 us; speedup 1.0000x reference)
//
#include <hip/hip_runtime.h>
#include <math.h>

// Problem constants (fixed by setup_inputs).
#define CC 4
#define NN 4096                  // vertices per class (== queries per class)
#define MM 4096
#define DD 32
#define GR 12                    // grid resolution per axis
#define NCELL (GR * GR * GR)     // 1728 cells per class
#define NC2 2048                 // padded cell count (2 cells/thread scan)
#define LPQ 16                   // lanes cooperating per query
#define BLK 1024                 // threads per block
#define QPB 64                   // queries per block

typedef unsigned long long u64;

__device__ __forceinline__ int cellof(float x) {
    int c = (int)(x * (float)GR);
    return min(max(c, 0), GR - 1);
}

// Branchless sorted-insert of key k into top-3 (k0<=k1<=k2).
// Keys are (f32_dist_bits << 13) | idx13: unsigned order == (dist, idx)
// lexicographic order == exact jax top_k semantics (stable ties).
__device__ __forceinline__ void ins3k(u64 k, u64& k0, u64& k1, u64& k2) {
    bool l2 = k < k2, l1 = k < k1, l0 = k < k0;
    k2 = l1 ? k1 : (l2 ? k : k2);
    k1 = l0 ? k0 : (l1 ? k : k1);
    k0 = l0 ? k : k0;
}

// ONE kernel, ONE graph node, no workspace. Each block privately builds the
// full cell index of its class in LDS (64 KB AoS float4 + starts), then
// answers 64 queries from LDS.
__global__ __launch_bounds__(BLK) void k_all(
    const float2* __restrict__ feat2,     // [CC*NN][16] float2
    const float* __restrict__ verts,      // [CC,NN,3]
    const float* __restrict__ nverts,     // [CC,MM,3]
    float2* __restrict__ out2)            // [CC*MM][16] float2
{
    __shared__ float4 sp[NN];                  // 64 KB {x,y,z,idx13 bits}
    __shared__ unsigned cnt[NC2];              // 8 KB  (counts -> cursor)
    __shared__ unsigned sstart[NCELL + 1];     // ~6.8 KB
    __shared__ unsigned wsum[BLK / 64];

    const int tid = threadIdx.x;
    const int c   = blockIdx.x >> 6;           // 64 blocks per class
    // Index bias so u64 tie-order matches jax column order per class:
    // c==0: real j -> j,   seeds -> 4096+s   (real cols < off-block cols)
    // c>0 : seeds -> s,    real j -> j+3     (off-block cols < real cols)
    const unsigned radd  = (c == 0) ? 0u : 3u;
    const unsigned sbase = (c == 0) ? 4096u : 0u;

    // ---- Phase A: stage 4 points/thread into registers; zero counts ----
    cnt[tid] = 0u; cnt[tid + 1024] = 0u;
    const float4* src4 = (const float4*)(verts + (size_t)c * NN * 3);
    const float4 fa = src4[3 * tid];
    const float4 fb = src4[3 * tid + 1];
    const float4 fc = src4[3 * tid + 2];
    const float px[4] = {fa.x, fa.w, fb.z, fc.y};
    const float py[4] = {fa.y, fb.x, fb.w, fc.z};
    const float pz[4] = {fa.z, fb.y, fc.x, fc.w};
    __syncthreads();                           // cnt zeroed

    int cell[4];
    #pragma unroll
    for (int u = 0; u < 4; ++u) {
        cell[u] = (cellof(px[u]) * GR + cellof(py[u])) * GR + cellof(pz[u]);
        atomicAdd(&cnt[cell[u]], 1u);
    }
    __syncthreads();

    // ---- Phase B: exclusive scan over 1728 counts (2 cells/thread) ----
    const int lane = tid & 63, wid = tid >> 6;
    const unsigned c0 = cnt[2 * tid], c1 = cnt[2 * tid + 1];
    const unsigned own = c0 + c1;
    unsigned incl = own;
    #pragma unroll
    for (int off = 1; off < 64; off <<= 1) {
        unsigned v = __shfl_up(incl, off);
        if (lane >= off) incl += v;
    }
    if (lane == 63) wsum[wid] = incl;
    __syncthreads();
    unsigned wbase = 0;
    for (int w = 0; w < wid; ++w) wbase += wsum[w];
    const unsigned excl = wbase + incl - own;
    __syncthreads();                           // all cnt reads done
    if (2 * tid < NCELL) {
        sstart[2 * tid]     = excl;
        sstart[2 * tid + 1] = excl + c0;
        cnt[2 * tid]     = excl;               // scatter cursor
        cnt[2 * tid + 1] = excl + c0;
    }
    if (tid == BLK - 1) sstart[NCELL] = excl + own;   // == NN
    __syncthreads();

    // ---- Phase C: scatter points into cell-sorted AoS ----
    #pragma unroll
    for (int u = 0; u < 4; ++u) {
        const unsigned pos = atomicAdd(&cnt[cell[u]], 1u);
        sp[pos] = make_float4(px[u], py[u], pz[u],
                              __uint_as_float((unsigned)(4 * tid + u) + radd));
    }
    __syncthreads();

    // ---- Phase D: 64 queries, 16 lanes each, all from LDS ----
    const int g = tid >> 4;                    // group 0..63
    const int t = tid & (LPQ - 1);
    const int m = (blockIdx.x << 6) + g;       // global query slot
    const float qx = nverts[3 * m + 0];
    const float qy = nverts[3 * m + 1];
    const float qz = nverts[3 * m + 2];

    const int cx = cellof(qx), cy = cellof(qy), cz = cellof(qz);
    const float cs = 1.0f / (float)GR;

    // Seeds: the off-block 1.0 entries, exact jax tie order via idx bias.
    const u64 SB = ((u64)0x3F800000u) << 13;
    u64 k0 = SB | (u64)(sbase + 0u);
    u64 k1 = SB | (u64)(sbase + 1u);
    u64 k2 = SB | (u64)(sbase + 2u);

    const int lz = max(cz - 1, 0), hz = min(cz + 1, GR - 1);

    // 9 z-column ranges from LDS starts (broadcast within group).
    unsigned aa[9], bb[9];
    #pragma unroll
    for (int j = 0; j < 9; ++j) {
        const int ppx = cx + j / 3 - 1, ppy = cy + j % 3 - 1;
        const bool ok = (ppx >= 0) & (ppx < GR) & (ppy >= 0) & (ppy < GR);
        const int rb = ok ? ((ppx * GR + ppy) * GR) : 0;
        const unsigned av = sstart[rb + lz];
        const unsigned bv = sstart[rb + hz + 1];
        aa[j] = av;
        bb[j] = ok ? bv : av;                  // empty if out of grid
    }

    // 1-deep predicated batch: 16 lanes cover 16 pts/column.
    float4 P[9];
    #pragma unroll
    for (int j = 0; j < 9; ++j) {
        const unsigned s0 = aa[j] + (unsigned)t;
        P[j] = sp[(s0 < bb[j]) ? s0 : 0u];
    }
    unsigned over = 0u;
    #pragma unroll
    for (int j = 0; j < 9; ++j) {
        const unsigned s0 = aa[j] + (unsigned)t;
        const float dx = P[j].x - qx, dy = P[j].y - qy, dz = P[j].z - qz;
        const float dd = fmaf(dx, dx, fmaf(dy, dy, dz * dz));
        u64 k = (((u64)__float_as_uint(dd)) << 13) |
                (u64)__float_as_uint(P[j].w);
        k = (s0 < bb[j]) ? k : ~0ull;
        ins3k(k, k0, k1, k2);
        over |= (bb[j] - aa[j] > (unsigned)LPQ) ? 1u : 0u;
    }
    if (over) {                                // rare: columns > 16 pts
        #pragma unroll 1
        for (int j = 0; j < 9; ++j) {
            for (unsigned s = aa[j] + LPQ + t; s < bb[j]; s += LPQ) {
                const float4 p = sp[s];
                const float dx = p.x - qx, dy = p.y - qy, dz = p.z - qz;
                const float dd = fmaf(dx, dx, fmaf(dy, dy, dz * dz));
                const u64 k = (((u64)__float_as_uint(dd)) << 13) |
                              (u64)__float_as_uint(p.w);
                ins3k(k, k0, k1, k2);
            }
        }
    }

    // Merge sorted triples across the 16-lane group.
    #pragma unroll
    for (int mask = 1; mask < LPQ; mask <<= 1) {
        const u64 e0 = __shfl_xor(k0, mask);
        const u64 e1 = __shfl_xor(k1, mask);
        const u64 e2 = __shfl_xor(k2, mask);
        ins3k(e0, k0, k1, k2);
        ins3k(e1, k0, k1, k2);
        ins3k(e2, k0, k1, k2);
    }

    // Certificate for r=1 (group-uniform); rare exact expanding rescan.
    {
        const int lx = max(cx - 1, 0), hx = min(cx + 1, GR - 1);
        const int ly = max(cy - 1, 0), hy = min(cy + 1, GR - 1);
        float rmin = 1e30f;
        if (lx > 0)      rmin = fminf(rmin, qx - (float)lx * cs);
        if (hx < GR - 1) rmin = fminf(rmin, (float)(hx + 1) * cs - qx);
        if (ly > 0)      rmin = fminf(rmin, qy - (float)ly * cs);
        if (hy < GR - 1) rmin = fminf(rmin, (float)(hy + 1) * cs - qy);
        if (lz > 0)      rmin = fminf(rmin, qz - (float)lz * cs);
        if (hz < GR - 1) rmin = fminf(rmin, (float)(hz + 1) * cs - qz);
        const float d2chk = __uint_as_float((unsigned)(k2 >> 13));

        if (!(d2chk <= rmin * rmin)) {         // P ~ 3e-3 per query
            for (int r = 2;; ++r) {
                k0 = SB | (u64)(sbase + 0u);
                k1 = SB | (u64)(sbase + 1u);
                k2 = SB | (u64)(sbase + 2u);
                const int Lx = max(cx - r, 0), Hx = min(cx + r, GR - 1);
                const int Ly = max(cy - r, 0), Hy = min(cy + r, GR - 1);
                const int Lz = max(cz - r, 0), Hz = min(cz + r, GR - 1);
                for (int ppx = Lx; ppx <= Hx; ++ppx) {
                    for (int ppy = Ly; ppy <= Hy; ++ppy) {
                        const int rb = (ppx * GR + ppy) * GR;
                        const unsigned a = sstart[rb + Lz];
                        const unsigned b = sstart[rb + Hz + 1];
                        for (unsigned s = a + t; s < b; s += LPQ) {
                            const float4 p = sp[s];
                            const float dx = p.x - qx, dy = p.y - qy,
                                        dz = p.z - qz;
                            const float dd =
                                fmaf(dx, dx, fmaf(dy, dy, dz * dz));
                            const u64 k =
                                (((u64)__float_as_uint(dd)) << 13) |
                                (u64)__float_as_uint(p.w);
                            ins3k(k, k0, k1, k2);
                        }
                    }
                }
                #pragma unroll
                for (int mask = 1; mask < LPQ; mask <<= 1) {
                    const u64 e0 = __shfl_xor(k0, mask);
                    const u64 e1 = __shfl_xor(k1, mask);
                    const u64 e2 = __shfl_xor(k2, mask);
                    ins3k(e0, k0, k1, k2);
                    ins3k(e1, k0, k1, k2);
                    ins3k(e2, k0, k1, k2);
                }
                float rm = 1e30f;
                if (Lx > 0)      rm = fminf(rm, qx - (float)Lx * cs);
                if (Hx < GR - 1) rm = fminf(rm, (float)(Hx + 1) * cs - qx);
                if (Ly > 0)      rm = fminf(rm, qy - (float)Ly * cs);
                if (Hy < GR - 1) rm = fminf(rm, (float)(Hy + 1) * cs - qy);
                if (Lz > 0)      rm = fminf(rm, qz - (float)Lz * cs);
                if (Hz < GR - 1) rm = fminf(rm, (float)(Hz + 1) * cs - qz);
                const bool full = (Lx == 0 && Ly == 0 && Lz == 0 &&
                                   Hx == GR - 1 && Hy == GR - 1 &&
                                   Hz == GR - 1);
                const float d2r = __uint_as_float((unsigned)(k2 >> 13));
                if (full || d2r <= rm * rm) break;
            }
        }
    }

    // Unpack keys -> (dist, feat row).
    const unsigned ia = (unsigned)(k0 & 0x1FFFull);
    const unsigned ib = (unsigned)(k1 & 0x1FFFull);
    const unsigned ic = (unsigned)(k2 & 0x1FFFull);
    const float d0 = __uint_as_float((unsigned)(k0 >> 13));
    const float d1 = __uint_as_float((unsigned)(k1 >> 13));
    const float d2 = __uint_as_float((unsigned)(k2 >> 13));
    int r0, r1, r2;
    if (c == 0) { r0 = ia; r1 = ib; r2 = ic; }   // real j or 4096+s
    else {
        r0 = (ia < 3u) ? (int)ia : ((int)ia - 3 + (c << 12));
        r1 = (ib < 3u) ? (int)ib : ((int)ib - 3 + (c << 12));
        r2 = (ic < 3u) ? (int)ic : ((int)ic - 3 + (c << 12));
    }

    // Fused epilogue: softmax(-d) + weighted feature gather (float2/lane).
    float w1 = expf(d0 - d1);
    float w2 = expf(d0 - d2);
    const float inv = 1.0f / (1.0f + w1 + w2);
    const float w0 = inv;
    w1 *= inv; w2 *= inv;

    const float2 a  = feat2[(size_t)r0 * 16 + t];
    const float2 b  = feat2[(size_t)r1 * 16 + t];
    const float2 gg = feat2[(size_t)r2 * 16 + t];
    float2 o;
    o.x = w0 * a.x + w1 * b.x + w2 * gg.x;
    o.y = w0 * a.y + w1 * b.y + w2 * gg.y;
    out2[(size_t)m * 16 + t] = o;              // natural order -> coalesced
}

extern "C" void kernel_launch(void* const* d_in, const int* in_sizes, int n_in,
                              void* d_out, int out_size, void* d_ws, size_t ws_size,
                              hipStream_t stream) {
    const float* feat   = (const float*)d_in[0];   // points_feat [1, C*N, D] f32
    const float* verts  = (const float*)d_in[1];   // vertices    [C, N, 3]  f32
    const float* nverts = (const float*)d_in[2];   // new_vertices[C, M, 3]  f32
    float* outp = (float*)d_out;                   // [1, C*M, D] f32

    k_all<<<dim3(CC * MM / QPB), dim3(BLK), 0, stream>>>(
        (const float2*)feat, verts, nverts, (float2*)outp);
}

// Round 13
// 67.294 us; speedup vs baseline: 1.0497x; 1.0497x over previous
//
#include <hip/hip_runtime.h>
#include <math.h>

// Problem constants (fixed by setup_inputs).
#define CC 4
#define NN 4096                  // vertices per class (== queries per class)
#define MM 4096
#define DD 32
#define GR 10                    // grid resolution per axis
#define NCELL (GR * GR * GR)     // 1000 cells per class
#define LPQ 16                   // lanes cooperating per query
#define BLK 1024                 // threads per block
#define QPB 64                   // queries per block

typedef unsigned long long u64;

__device__ __forceinline__ int cellof(float x) {
    int c = (int)(x * (float)GR);
    return min(max(c, 0), GR - 1);
}

// Branchless sorted-insert of key k into top-3 (k0<=k1<=k2).
// Keys are (f32_dist_bits << 13) | idx13: unsigned order == (dist, idx)
// lexicographic == exact jax top_k semantics. Crucially this is INVARIANT
// to the (nondeterministic) LDS counting-sort insertion order — R12's
// post-timing divergence came from order-dependent tie-breaking.
__device__ __forceinline__ void ins3k(u64 k, u64& k0, u64& k1, u64& k2) {
    bool l2 = k < k2, l1 = k < k1, l0 = k < k0;
    k2 = l1 ? k1 : (l2 ? k : k2);
    k1 = l0 ? k0 : (l1 ? k : k1);
    k0 = l0 ? k : k0;
}

// ONE kernel, ONE graph node, no workspace. Each block privately builds the
// full cell index of its class in LDS (64 KB AoS float4 {x,y,z,idx bits}),
// then answers 64 queries from LDS.
__global__ __launch_bounds__(BLK) void k_all(
    const float2* __restrict__ feat2,     // [CC*NN][16] float2
    const float* __restrict__ verts,      // [CC,NN,3]
    const float* __restrict__ nverts,     // [CC,MM,3]
    float2* __restrict__ out2)            // [CC*MM][16] float2
{
    __shared__ float4 sp[NN];                  // 64 KB {x,y,z,idx bits}
    __shared__ unsigned cnt[NCELL];            // 4 KB  (counts -> cursor)
    __shared__ unsigned sstart[NCELL + 1];     // 4 KB  (exclusive starts)
    __shared__ unsigned wsum[BLK / 64];

    const int tid = threadIdx.x;
    const int c   = blockIdx.x >> 6;           // 64 blocks per class
    // Index bias so u64 tie-order matches jax column order per class:
    // c==0: real j -> j, seeds -> 4096+s (real cols before off-block cols)
    // c>0 : seeds -> s,  real j -> j+3   (off-block cols before real cols)
    const unsigned radd  = (c == 0) ? 0u : 3u;
    const unsigned sbase = (c == 0) ? 4096u : 0u;

    // ---- Phase A: stage 4 points/thread into registers; zero counts ----
    if (tid < NCELL) cnt[tid] = 0u;
    const float4* src4 = (const float4*)(verts + (size_t)c * NN * 3);
    const float4 fa = src4[3 * tid];
    const float4 fb = src4[3 * tid + 1];
    const float4 fc = src4[3 * tid + 2];
    const float px[4] = {fa.x, fa.w, fb.z, fc.y};
    const float py[4] = {fa.y, fb.x, fb.w, fc.z};
    const float pz[4] = {fa.z, fb.y, fc.x, fc.w};
    __syncthreads();                           // cnt zeroed

    int cell[4];
    #pragma unroll
    for (int u = 0; u < 4; ++u) {
        cell[u] = (cellof(px[u]) * GR + cellof(py[u])) * GR + cellof(pz[u]);
        atomicAdd(&cnt[cell[u]], 1u);
    }
    __syncthreads();

    // ---- Phase B: exclusive scan of 1000 counts (thread t owns cell t) ----
    const int lane = tid & 63, wid = tid >> 6;
    const unsigned own = (tid < NCELL) ? cnt[tid] : 0u;
    unsigned incl = own;
    #pragma unroll
    for (int off = 1; off < 64; off <<= 1) {
        unsigned v = __shfl_up(incl, off);
        if (lane >= off) incl += v;
    }
    if (lane == 63) wsum[wid] = incl;
    __syncthreads();                           // also fences own= reads
    unsigned wbase = 0;
    for (int w = 0; w < wid; ++w) wbase += wsum[w];
    if (tid < NCELL) {
        const unsigned excl = wbase + incl - own;
        cnt[tid]    = excl;                    // scatter cursor
        sstart[tid] = excl;
    }
    if (tid == BLK - 1) sstart[NCELL] = wbase + incl;   // == NN
    __syncthreads();

    // ---- Phase C: scatter points into cell-sorted AoS (1 b128 write) ----
    #pragma unroll
    for (int u = 0; u < 4; ++u) {
        const unsigned pos = atomicAdd(&cnt[cell[u]], 1u);
        sp[pos] = make_float4(px[u], py[u], pz[u],
                              __uint_as_float((unsigned)(4 * tid + u) + radd));
    }
    __syncthreads();

    // ---- Phase D: 64 queries, 16 lanes each, all from LDS ----
    const int g = tid >> 4;                    // group 0..63
    const int t = tid & (LPQ - 1);
    const int m = (blockIdx.x << 6) + g;       // global query slot
    const float qx = nverts[3 * m + 0];
    const float qy = nverts[3 * m + 1];
    const float qz = nverts[3 * m + 2];

    const int cx = cellof(qx), cy = cellof(qy), cz = cellof(qz);
    const float cs = 1.0f / (float)GR;

    // Seeds: the off-block 1.0 entries, exact jax tie order via idx bias.
    const u64 SB = ((u64)0x3F800000u) << 13;   // f32 1.0 bits
    u64 k0 = SB | (u64)(sbase + 0u);
    u64 k1 = SB | (u64)(sbase + 1u);
    u64 k2 = SB | (u64)(sbase + 2u);

    const int lz = max(cz - 1, 0), hz = min(cz + 1, GR - 1);

    // 9 z-column ranges from LDS starts (broadcast within group).
    unsigned aa[9], bb[9];
    #pragma unroll
    for (int j = 0; j < 9; ++j) {
        const int ppx = cx + j / 3 - 1, ppy = cy + j % 3 - 1;
        const bool ok = (ppx >= 0) & (ppx < GR) & (ppy >= 0) & (ppy < GR);
        const int rb = ok ? ((ppx * GR + ppy) * GR) : 0;
        const unsigned av = sstart[rb + lz];
        const unsigned bv = sstart[rb + hz + 1];
        aa[j] = av;
        bb[j] = ok ? bv : av;                  // empty if out of grid
    }

    // 2-deep predicated batch: lanes t and t+16 cover 32 pts/column.
    unsigned over = 0u;
    #pragma unroll
    for (int j = 0; j < 9; ++j) {
        const unsigned s0 = aa[j] + (unsigned)t, s1 = s0 + LPQ;
        const float4 p0 = sp[(s0 < bb[j]) ? s0 : 0u];
        const float4 p1 = sp[(s1 < bb[j]) ? s1 : 0u];
        float dx = p0.x - qx, dy = p0.y - qy, dz = p0.z - qz;
        const float dd = fmaf(dx, dx, fmaf(dy, dy, dz * dz));
        u64 ka = (((u64)__float_as_uint(dd)) << 13) |
                 (u64)__float_as_uint(p0.w);
        ka = (s0 < bb[j]) ? ka : ~0ull;
        ins3k(ka, k0, k1, k2);
        dx = p1.x - qx; dy = p1.y - qy; dz = p1.z - qz;
        const float de = fmaf(dx, dx, fmaf(dy, dy, dz * dz));
        u64 kb = (((u64)__float_as_uint(de)) << 13) |
                 (u64)__float_as_uint(p1.w);
        kb = (s1 < bb[j]) ? kb : ~0ull;
        ins3k(kb, k0, k1, k2);
        over |= (bb[j] - aa[j] > 2u * LPQ) ? 1u : 0u;
    }
    if (over) {                                // rare: columns > 32 pts
        #pragma unroll 1
        for (int j = 0; j < 9; ++j) {
            for (unsigned s = aa[j] + 2u * LPQ + t; s < bb[j]; s += LPQ) {
                const float4 p = sp[s];
                const float dx = p.x - qx, dy = p.y - qy, dz = p.z - qz;
                const float dd = fmaf(dx, dx, fmaf(dy, dy, dz * dz));
                const u64 k = (((u64)__float_as_uint(dd)) << 13) |
                              (u64)__float_as_uint(p.w);
                ins3k(k, k0, k1, k2);
            }
        }
    }

    // Merge sorted triples across the 16-lane group.
    #pragma unroll
    for (int mask = 1; mask < LPQ; mask <<= 1) {
        const u64 e0 = __shfl_xor(k0, mask);
        const u64 e1 = __shfl_xor(k1, mask);
        const u64 e2 = __shfl_xor(k2, mask);
        ins3k(e0, k0, k1, k2);
        ins3k(e1, k0, k1, k2);
        ins3k(e2, k0, k1, k2);
    }

    // Certificate for r=1 (group-uniform); rare exact expanding rescan.
    {
        const int lx = max(cx - 1, 0), hx = min(cx + 1, GR - 1);
        const int ly = max(cy - 1, 0), hy = min(cy + 1, GR - 1);
        float rmin = 1e30f;
        if (lx > 0)      rmin = fminf(rmin, qx - (float)lx * cs);
        if (hx < GR - 1) rmin = fminf(rmin, (float)(hx + 1) * cs - qx);
        if (ly > 0)      rmin = fminf(rmin, qy - (float)ly * cs);
        if (hy < GR - 1) rmin = fminf(rmin, (float)(hy + 1) * cs - qy);
        if (lz > 0)      rmin = fminf(rmin, qz - (float)lz * cs);
        if (hz < GR - 1) rmin = fminf(rmin, (float)(hz + 1) * cs - qz);
        const float d2chk = __uint_as_float((unsigned)(k2 >> 13));

        if (!(d2chk <= rmin * rmin)) {         // P ~ 5.8e-6 per query
            for (int r = 2;; ++r) {
                k0 = SB | (u64)(sbase + 0u);
                k1 = SB | (u64)(sbase + 1u);
                k2 = SB | (u64)(sbase + 2u);
                const int Lx = max(cx - r, 0), Hx = min(cx + r, GR - 1);
                const int Ly = max(cy - r, 0), Hy = min(cy + r, GR - 1);
                const int Lz = max(cz - r, 0), Hz = min(cz + r, GR - 1);
                for (int ppx = Lx; ppx <= Hx; ++ppx) {
                    for (int ppy = Ly; ppy <= Hy; ++ppy) {
                        const int rb = (ppx * GR + ppy) * GR;
                        const unsigned a = sstart[rb + Lz];
                        const unsigned b = sstart[rb + Hz + 1];
                        for (unsigned s = a + t; s < b; s += LPQ) {
                            const float4 p = sp[s];
                            const float dx = p.x - qx, dy = p.y - qy,
                                        dz = p.z - qz;
                            const float dd =
                                fmaf(dx, dx, fmaf(dy, dy, dz * dz));
                            const u64 k =
                                (((u64)__float_as_uint(dd)) << 13) |
                                (u64)__float_as_uint(p.w);
                            ins3k(k, k0, k1, k2);
                        }
                    }
                }
                #pragma unroll
                for (int mask = 1; mask < LPQ; mask <<= 1) {
                    const u64 e0 = __shfl_xor(k0, mask);
                    const u64 e1 = __shfl_xor(k1, mask);
                    const u64 e2 = __shfl_xor(k2, mask);
                    ins3k(e0, k0, k1, k2);
                    ins3k(e1, k0, k1, k2);
                    ins3k(e2, k0, k1, k2);
                }
                float rm = 1e30f;
                if (Lx > 0)      rm = fminf(rm, qx - (float)Lx * cs);
                if (Hx < GR - 1) rm = fminf(rm, (float)(Hx + 1) * cs - qx);
                if (Ly > 0)      rm = fminf(rm, qy - (float)Ly * cs);
                if (Hy < GR - 1) rm = fminf(rm, (float)(Hy + 1) * cs - qy);
                if (Lz > 0)      rm = fminf(rm, qz - (float)Lz * cs);
                if (Hz < GR - 1) rm = fminf(rm, (float)(Hz + 1) * cs - qz);
                const bool full = (Lx == 0 && Ly == 0 && Lz == 0 &&
                                   Hx == GR - 1 && Hy == GR - 1 &&
                                   Hz == GR - 1);
                const float d2r = __uint_as_float((unsigned)(k2 >> 13));
                if (full || d2r <= rm * rm) break;
            }
        }
    }

    // Unpack keys -> (dist, feature row) with exact jax column mapping.
    const unsigned ia = (unsigned)(k0 & 0x1FFFull);
    const unsigned ib = (unsigned)(k1 & 0x1FFFull);
    const unsigned ic = (unsigned)(k2 & 0x1FFFull);
    const float d0 = __uint_as_float((unsigned)(k0 >> 13));
    const float d1 = __uint_as_float((unsigned)(k1 >> 13));
    const float d2 = __uint_as_float((unsigned)(k2 >> 13));
    int r0, r1, r2;
    if (c == 0) { r0 = (int)ia; r1 = (int)ib; r2 = (int)ic; }
    else {
        r0 = (ia < 3u) ? (int)ia : ((int)ia - 3 + (c << 12));
        r1 = (ib < 3u) ? (int)ib : ((int)ib - 3 + (c << 12));
        r2 = (ic < 3u) ? (int)ic : ((int)ic - 3 + (c << 12));
    }

    // Fused epilogue: softmax(-d) + weighted feature gather (float2/lane).
    float w1 = __expf(d0 - d1);
    float w2 = __expf(d0 - d2);
    const float inv = 1.0f / (1.0f + w1 + w2);
    const float w0 = inv;
    w1 *= inv; w2 *= inv;

    const float2 a  = feat2[(size_t)r0 * 16 + t];
    const float2 b  = feat2[(size_t)r1 * 16 + t];
    const float2 gg = feat2[(size_t)r2 * 16 + t];
    float2 o;
    o.x = w0 * a.x + w1 * b.x + w2 * gg.x;
    o.y = w0 * a.y + w1 * b.y + w2 * gg.y;
    out2[(size_t)m * 16 + t] = o;              // natural order -> coalesced
}

extern "C" void kernel_launch(void* const* d_in, const int* in_sizes, int n_in,
                              void* d_out, int out_size, void* d_ws, size_t ws_size,
                              hipStream_t stream) {
    const float* feat   = (const float*)d_in[0];   // points_feat [1, C*N, D] f32
    const float* verts  = (const float*)d_in[1];   // vertices    [C, N, 3]  f32
    const float* nverts = (const float*)d_in[2];   // new_vertices[C, M, 3]  f32
    float* outp = (float*)d_out;                   // [1, C*M, D] f32

    k_all<<<dim3(CC * MM / QPB), dim3(BLK), 0, stream>>>(
        (const float2*)feat, verts, nverts, (float2*)outp);
}